// Round 8
// baseline (150.138 us; speedup 1.0000x reference)
//
#include <hip/hip_runtime.h>

// SelfAttention: B=4, S=4096, E=1024, H=64, single head, causal, p=0.
// I/O fp32, internals bf16 MFMA.
// Round 19: proj_all = real block-parallelism (the never-tried lever).
//  - R13->R16 "occupancy win" was misattributed: both ran 2 blocks/CU
//    (512 blocks / 256 CU); launch_bounds slack never bound. Counted-vmcnt
//    pipelines at 8 waves/CU were null x3 (R15/R17/R18).
//  - Now: 1024 blocks x 16 rows, LDS 8 KB (xs dbuf only), W JIT to regs
//    (R16-proven), launch_bounds(256,4) -> 4 blocks/CU, 16 waves/CU,
//    blocks anti-phase across private barriers. Per-wave compute per step
//    unchanged (6 MFMA, 32 f2bf); staging per block halved.
//  - Simple __syncthreads dbuf (pipeline asm reverted - proven best).
//  - attn = proven R12; combine = R18 float4; transpose unchanged.

using short8 = __attribute__((ext_vector_type(8))) short;
using f32x4  = __attribute__((ext_vector_type(4))) float;

#define MFMA16(A, B, C) __builtin_amdgcn_mfma_f32_16x16x32_bf16((A), (B), (C), 0, 0, 0)

typedef const __attribute__((address_space(1))) void* gas_ptr;
typedef __attribute__((address_space(3))) void*       las_ptr;

__device__ __forceinline__ void gload16(const void* g, void* l) {
    // async global->LDS, 16B/lane, LDS dst = base + lane*16 (wave-uniform base)
    __builtin_amdgcn_global_load_lds((gas_ptr)g, (las_ptr)l, 16, 0, 0);
}

__device__ __forceinline__ unsigned short f2bf(float f) {
    unsigned u = __builtin_bit_cast(unsigned, f);
    u += 0x7fffu + ((u >> 16) & 1u);   // RNE
    return (unsigned short)(u >> 16);
}
__device__ __forceinline__ float bf2f(unsigned short u) {
    unsigned v = ((unsigned)u) << 16;
    return __builtin_bit_cast(float, v);
}

__device__ __forceinline__ float exp2_fast(float x) {
#if __has_builtin(__builtin_amdgcn_exp2f)
    return __builtin_amdgcn_exp2f(x);
#else
    float r;
    asm("v_exp_f32 %0, %1" : "=v"(r) : "v"(x));
    return r;
#endif
}

// ------------------------------------------------- W frag-order pack
__global__ __launch_bounds__(256) void transpose_w(
    const float* __restrict__ Wq,
    const float* __restrict__ Wk,
    const float* __restrict__ Wv,
    unsigned short* __restrict__ Ws)
{
    int o = blockIdx.x * 256 + threadIdx.x;   // 196608 total
    if (o < 196608) {
        int j    = o & 7;
        int l    = (o >> 3) & 63;
        int g    = (o >> 9) & 7;
        int rem  = o >> 12;        // sk*3 + mt
        int mt   = rem % 3;
        int sk   = rem / 3;
        int c    = g >> 2, nt = g & 3;
        int quad = l >> 4, n  = l & 15;
        int e    = sk * 64 + c * 32 + quad * 8 + j;
        int h    = nt * 16 + n;
        const float* W = (mt == 0) ? Wq : (mt == 1) ? Wk : Wv;
        Ws[o] = f2bf(W[e * 64 + h]);
    }
}

// ---------------------------------------------------------------- projection
// 1024 blocks x 256 threads, 16 rows/block. 4 waves = ch (nt column) 0..3;
// all waves share the 16 rows. x staged via gload16 into 8 KB LDS dbuf
// (1 load/wave/step); W JIT to registers. 4 blocks/CU, 16 waves/CU.
__global__ __launch_bounds__(256, 4) void proj_all(
    const float* __restrict__ x,             // [16384][1024] fp32
    const unsigned short* __restrict__ Ws,   // [16][3][8][64][8] bf16 frag-order
    unsigned short* __restrict__ Qo,         // [16384][64] bf16
    unsigned short* __restrict__ Ko,         // [16384][64] bf16
    unsigned short* __restrict__ Vto)        // [4][80][4096] bf16 (V^T)
{
    const int m0   = blockIdx.x * 16;
    const int tid  = threadIdx.x;
    const int lane = tid & 63;
    const int ch   = tid >> 6;     // 0..3 = nt column
    const int quad = lane >> 4;
    const int n    = lane & 15;

    __shared__ __align__(16) float xs[2][4][64][4];   // 8 KB

    const f32x4 zero4 = {0.f, 0.f, 0.f, 0.f};
    f32x4 acc[3];                  // [mt]
    acc[0] = zero4; acc[1] = zero4; acc[2] = zero4;

    // stage k-step t: exactly 1 gload16 per wave (wave ch stages row-group ch)
    auto stage = [&](int t, int p) {
        int k0    = t * 64;
        int chunk = n ^ (quad << 2);
        gload16(x + (size_t)(m0 + 4 * ch + quad) * 1024 + k0 + chunk * 4,
                &xs[p][ch][0][0]);
    };

    stage(0, 0);
    __syncthreads();

    int p = 0;
    for (int t = 0; t < 16; ++t) {
        if (t < 15) stage(t + 1, p ^ 1);

        // W JIT: 6 panels straight to registers (coalesced 1 KB each;
        // all 4 blocks on a CU stream the same panels -> L1 hits)
        const unsigned short* wp = Ws + (((size_t)t * 24) << 9) + (size_t)lane * 8;
        short8 w0[3], w1[3];
        #pragma unroll
        for (int mt = 0; mt < 3; ++mt) {
            w0[mt] = *(const short8*)(wp + ((size_t)(mt * 8 + ch)     << 9));
            w1[mt] = *(const short8*)(wp + ((size_t)(mt * 8 + 4 + ch) << 9));
        }

        int sub = n & 3, s = sub << 2;
        const float* xp = &xs[p][n >> 2][0][0] + sub * 64;
        f32x4 u0 = *(const f32x4*)(xp + (((2 * quad)     ^ s) << 2));
        f32x4 u1 = *(const f32x4*)(xp + (((2 * quad + 1) ^ s) << 2));
        f32x4 u2 = *(const f32x4*)(xp + (((8 + 2 * quad) ^ s) << 2));
        f32x4 u3 = *(const f32x4*)(xp + (((9 + 2 * quad) ^ s) << 2));
        short8 a0, a1;
        #pragma unroll
        for (int j = 0; j < 4; ++j) {
            a0[j]     = (short)f2bf(u0[j]);
            a0[4 + j] = (short)f2bf(u1[j]);
            a1[j]     = (short)f2bf(u2[j]);
            a1[4 + j] = (short)f2bf(u3[j]);
        }
        #pragma unroll
        for (int mt = 0; mt < 3; ++mt) {
            acc[mt] = MFMA16(a0, w0[mt], acc[mt]);
            acc[mt] = MFMA16(a1, w1[mt], acc[mt]);
        }

        __syncthreads();
        p ^= 1;
    }

    const int h = ch * 16 + n;
    #pragma unroll
    for (int r = 0; r < 4; ++r) {
        int m = m0 + quad * 4 + r;
        Qo[(size_t)m * 64 + h] = f2bf(acc[0][r]);
        Ko[(size_t)m * 64 + h] = f2bf(acc[1][r]);
        int b = m >> 12, s2 = m & 4095;
        Vto[((size_t)(b * 80 + h)) * 4096 + s2] = f2bf(acc[2][r]);
    }
}

// ---------------------------------------------------------------- attention
// 128-row Q-tile, 4 waves x 32 rows. 50 KB LDS -> 3 blocks/CU.
template <int SPLIT>
__device__ __forceinline__ void attn_body(
    const unsigned short* __restrict__ Q,
    const unsigned short* __restrict__ K,
    const unsigned short* __restrict__ Vt,   // [4][80][4096] (rows >=64 unused)
    float* __restrict__ dst,
    int b, int r0, int kt0, int kt1)
{
    const int tid  = threadIdx.x;
    const int lane = tid & 63;
    const int wv   = tid >> 6;     // 0..3
    const int quad = lane >> 4;
    const int n    = lane & 15;
    const int ktmask = r0 >> 6;

    __shared__ __align__(16) short kf[2][8][64][8];            // 16 KB
    __shared__ __align__(16) short vf[2][8][64][8];            // 16 KB
    __shared__ __align__(16) unsigned short pbuf[4][32][72];   // 18 KB

    // fold 0.125 (H^-0.5) * log2(e) so the score feeds v_exp_f32 (2^x) directly
    short8 qa[2][2];
    #pragma unroll
    for (int rg = 0; rg < 2; ++rg) {
        const unsigned short* qp =
            Q + (size_t)(b * 4096 + r0 + wv * 32 + rg * 16 + n) * 64 + quad * 8;
        #pragma unroll
        for (int j = 0; j < 8; ++j) {
            qa[rg][0][j] = (short)f2bf(bf2f(qp[j])      * 0.18033688f);
            qa[rg][1][j] = (short)f2bf(bf2f(qp[32 + j]) * 0.18033688f);
        }
    }

    const f32x4 zero4 = {0.f, 0.f, 0.f, 0.f};
    f32x4 oacc[2][4];
    float lacc[2][4];
    #pragma unroll
    for (int rg = 0; rg < 2; ++rg)
        #pragma unroll
        for (int nt = 0; nt < 4; ++nt) { oacc[rg][nt] = zero4; lacc[rg][nt] = 0.f; }

    const unsigned short* kbase = K  + ((size_t)b * 4096 + n) * 64 + quad * 8;
    const unsigned short* vbase = Vt + ((size_t)b * 80 + n) * 4096 + quad * 8;

    auto stage = [&](int kt, int p) {
        #pragma unroll
        for (int it = 0; it < 4; ++it) {
            int f = wv + 4 * it;               // 0..15, 4 loads per wave
            if (f < 8) {
                int c = f >> 2, nt = f & 3;
                gload16(kbase + (size_t)(kt * 64 + nt * 16) * 64 + c * 32, &kf[p][f][0][0]);
            } else {
                int pnl = f - 8;               // 0..7
                int nt = pnl >> 1, c = pnl & 1;
                gload16(vbase + (size_t)nt * 16 * 4096 + kt * 64 + c * 32, &vf[p][pnl][0][0]);
            }
        }
    };

    int p = 0;
    stage(kt0, 0);
    __syncthreads();

    for (int kt = kt0; kt <= kt1; ++kt) {
        if (kt < kt1) stage(kt + 1, p ^ 1);

        // QK^T: nt-outer so each kf panel is read once, frags live 8 VGPR
        f32x4 sacc[2][4];
        #pragma unroll
        for (int rg = 0; rg < 2; ++rg)
            #pragma unroll
            for (int nt = 0; nt < 4; ++nt) sacc[rg][nt] = zero4;

        #pragma unroll
        for (int nt = 0; nt < 4; ++nt) {
            short8 ka = *(const short8*)(&kf[p][nt][lane][0]);
            short8 kb = *(const short8*)(&kf[p][4 + nt][lane][0]);
            #pragma unroll
            for (int rg = 0; rg < 2; ++rg) {
                sacc[rg][nt] = MFMA16(qa[rg][0], ka, sacc[rg][nt]);
                sacc[rg][nt] = MFMA16(qa[rg][1], kb, sacc[rg][nt]);
            }
        }

        if (kt >= ktmask) {
            #pragma unroll
            for (int rg = 0; rg < 2; ++rg) {
                int qg = r0 + wv * 32 + rg * 16 + quad * 4;
                #pragma unroll
                for (int nt = 0; nt < 4; ++nt)
                    #pragma unroll
                    for (int r = 0; r < 4; ++r) {
                        int key = kt * 64 + nt * 16 + n;
                        if (key > qg + r) sacc[rg][nt][r] = -1e30f;
                    }
            }
        }

        // exp2 + pbuf write + per-lane bf16 row-sum (denominator, replaces
        // the ones-column MFMA: sums the SAME bf16 values in fp32)
        #pragma unroll
        for (int rg = 0; rg < 2; ++rg)
            #pragma unroll
            for (int r = 0; r < 4; ++r) {
                float rs = 0.f;
                #pragma unroll
                for (int nt = 0; nt < 4; ++nt) {
                    unsigned short pv = f2bf(exp2_fast(sacc[rg][nt][r]));
                    pbuf[wv][rg * 16 + quad * 4 + r][nt * 16 + n] = pv;
                    rs += bf2f(pv);
                }
                lacc[rg][r] += rs;
            }

        // PV: nt-outer, vf panels read once
        short8 pa[2][2];
        #pragma unroll
        for (int rg = 0; rg < 2; ++rg) {
            pa[rg][0] = *(const short8*)(&pbuf[wv][rg * 16 + n][quad * 8]);
            pa[rg][1] = *(const short8*)(&pbuf[wv][rg * 16 + n][32 + quad * 8]);
        }
        #pragma unroll
        for (int nt = 0; nt < 4; ++nt) {
            short8 va = *(const short8*)(&vf[p][2 * nt][lane][0]);
            short8 vb = *(const short8*)(&vf[p][2 * nt + 1][lane][0]);
            #pragma unroll
            for (int rg = 0; rg < 2; ++rg) {
                oacc[rg][nt] = MFMA16(pa[rg][0], va, oacc[rg][nt]);
                oacc[rg][nt] = MFMA16(pa[rg][1], vb, oacc[rg][nt]);
            }
        }

        __syncthreads();
        p ^= 1;
    }

    // denominator: reduce over the 16 n-lanes of each quad group
    #pragma unroll
    for (int rg = 0; rg < 2; ++rg)
        #pragma unroll
        for (int r = 0; r < 4; ++r) {
            float v = lacc[rg][r];
            v += __shfl_xor(v, 1);
            v += __shfl_xor(v, 2);
            v += __shfl_xor(v, 4);
            v += __shfl_xor(v, 8);
            lacc[rg][r] = v;
        }

    if (SPLIT) {
        // record: O[128][64] fp32 (unnormalized) + l[128] at +8192
        #pragma unroll
        for (int rg = 0; rg < 2; ++rg)
            #pragma unroll
            for (int r = 0; r < 4; ++r) {
                int row = wv * 32 + rg * 16 + quad * 4 + r;
                #pragma unroll
                for (int nt = 0; nt < 4; ++nt)
                    dst[row * 64 + nt * 16 + n] = oacc[rg][nt][r];
                if (n == 0) dst[8192 + row] = lacc[rg][r];
            }
    } else {
        #pragma unroll
        for (int rg = 0; rg < 2; ++rg)
            #pragma unroll
            for (int r = 0; r < 4; ++r) {
                float inv = 1.f / lacc[rg][r];
                int q = r0 + wv * 32 + rg * 16 + quad * 4 + r;
                #pragma unroll
                for (int nt = 0; nt < 4; ++nt)
                    dst[(size_t)(b * 4096 + q) * 64 + nt * 16 + n] = oacc[rg][nt][r] * inv;
            }
    }
}

// Split-K: block -> (b, qtile128, chunk of 8 kt). 4 x 144 = 576 blocks.
__global__ __launch_bounds__(256, 3) void attn_part(
    const unsigned short* __restrict__ Q,
    const unsigned short* __restrict__ K,
    const unsigned short* __restrict__ Vt,
    float* __restrict__ Part)
{
    int id = blockIdx.x;
    int b  = id & 3;
    int t  = 143 - (id >> 2);              // heavy chunks first
    int g  = 0;
    while (2 * (g + 1) * (g + 2) <= t) ++g;
    int u  = t - 2 * g * (g + 1);
    int qt = 4 * g + u / (g + 1);
    int c  = u - (u / (g + 1)) * (g + 1);

    int r0  = qt * 128;
    int kt0 = c * 8;
    int kt1 = min(kt0 + 7, 2 * qt + 1);

    float* dst = Part + (size_t)(b * 144 + t) * 8320;
    attn_body<1>(Q, K, Vt, dst, b, r0, kt0, kt1);
}

// Monolithic fallback (ws too small).
__global__ __launch_bounds__(256, 3) void attn_mono(
    const unsigned short* __restrict__ Q,
    const unsigned short* __restrict__ K,
    const unsigned short* __restrict__ Vt,
    float* __restrict__ out)
{
    int id = blockIdx.x;
    int qt = 31 - (id >> 2);
    int b  = id & 3;
    attn_body<0>(Q, K, Vt, out, b, qt * 128, 0, 2 * qt + 1);
}

// ---------------------------------------------------------------- combine
// 1024 blocks = (4 b x 32 qt) x 8 slices of 16 rows. Each thread owns 4
// CONSECUTIVE floats -> float4 loads/stores (G13); c outermost.
__global__ __launch_bounds__(256) void combine(
    const float* __restrict__ Part, float* __restrict__ out)
{
    int id    = blockIdx.x;
    int slice = id & 7;                 // 16-row slice
    int bq    = id >> 3;
    int b     = bq & 3;
    int qt    = bq >> 2;
    int g     = qt >> 2;
    int nc    = g + 1;
    int t0    = 2 * g * (g + 1) + (qt & 3) * (g + 1);
    const float* P0 = Part + (size_t)(b * 144 + t0) * 8320;

    int tid = threadIdx.x;

    // denominators for this slice's 16 rows (parallel across c via 8 regs)
    __shared__ float invden[16];
    if (tid < 16) {
        float d[8] = {0, 0, 0, 0, 0, 0, 0, 0};
        #pragma unroll 8
        for (int c = 0; c < 8; ++c)
            if (c < nc) d[c] = P0[c * 8320 + 8192 + slice * 16 + tid];
        invden[tid] = 1.f / (((d[0] + d[1]) + (d[2] + d[3])) +
                             ((d[4] + d[5]) + (d[6] + d[7])));
    }

    // 1024 elements: 4 consecutive per thread (float4), c outermost
    f32x4 acc = {0.f, 0.f, 0.f, 0.f};
    const float* Pe = P0 + slice * 1024 + tid * 4;
    for (int c = 0; c < nc; ++c) {
        f32x4 v = *(const f32x4*)(Pe + (size_t)c * 8320);
        acc += v;
    }

    __syncthreads();
    float inv = invden[tid >> 4];       // row = (tid*4)>>6
    f32x4 o = {acc[0] * inv, acc[1] * inv, acc[2] * inv, acc[3] * inv};
    *(f32x4*)(out + ((size_t)b * 4096 + qt * 128 + slice * 16) * 64 + tid * 4) = o;
}

// ---------------------------------------------------------------- launcher
extern "C" void kernel_launch(void* const* d_in, const int* in_sizes, int n_in,
                              void* d_out, int out_size, void* d_ws, size_t ws_size,
                              hipStream_t stream) {
    const float* x  = (const float*)d_in[0];
    const float* Wq = (const float*)d_in[1];
    const float* Wk = (const float*)d_in[2];
    const float* Wv = (const float*)d_in[3];
    float* outp = (float*)d_out;
    unsigned short* ws = (unsigned short*)d_ws;

    // ws (bf16 elems): Q 1M | K 1M | Vt 4*80*4096 | Ws 192K, then fp32 partials
    unsigned short* Qw  = ws;
    unsigned short* Kw  = ws + 1048576;
    unsigned short* Vtw = ws + 2097152;            // 1310720 elems
    unsigned short* Wsp = ws + 3407872;            // 196608 elems -> end 3604480

    size_t part_off = ((size_t)3604480 * 2 + 255) & ~(size_t)255;
    size_t need     = part_off + (size_t)4 * 144 * 8320 * 4;
    float* Part = (float*)((char*)d_ws + part_off);

    transpose_w<<<dim3(768), dim3(256), 0, stream>>>(Wq, Wk, Wv, Wsp);
    proj_all<<<dim3(1024), dim3(256), 0, stream>>>(x, Wsp, Qw, Kw, Vtw);

    if (ws_size >= need) {
        attn_part<<<dim3(576), dim3(256), 0, stream>>>(Qw, Kw, Vtw, Part);
        combine<<<dim3(1024), dim3(256), 0, stream>>>(Part, outp);
    } else {
        attn_mono<<<dim3(128), dim3(256), 0, stream>>>(Qw, Kw, Vtw, outp);
    }
}

// Round 10
// 140.823 us; speedup vs baseline: 1.0661x; 1.0661x over previous
//
#include <hip/hip_runtime.h>

// SelfAttention: B=4, S=4096, E=1024, H=64, single head, causal, p=0.
// I/O fp32, internals bf16 MFMA.
// Round 21: exact R17 revert (proven 141.3us) + ONE safe change:
//  - attn denominator summed from pre-rounding f32 exp2 values (drops 32
//    bf2f/iter/wave). pbuf keeps manual-RNE f2bf (bit-identical to R17).
//  - R20 post-mortem: hand-written v_cvt_pk_bf16_f32 asm produced garbage
//    (absmax 3e29) -> BANNED this session; guide m240 warns against it.
//  - proj = R17 counted-vmcnt 3-buf structure; combine/transpose = R17.

using short8 = __attribute__((ext_vector_type(8))) short;
using f32x4  = __attribute__((ext_vector_type(4))) float;

#define MFMA16(A, B, C) __builtin_amdgcn_mfma_f32_16x16x32_bf16((A), (B), (C), 0, 0, 0)

typedef const __attribute__((address_space(1))) void* gas_ptr;
typedef __attribute__((address_space(3))) void*       las_ptr;

__device__ __forceinline__ void gload16(const void* g, void* l) {
    // async global->LDS, 16B/lane, LDS dst = base + lane*16 (wave-uniform base)
    __builtin_amdgcn_global_load_lds((gas_ptr)g, (las_ptr)l, 16, 0, 0);
}

__device__ __forceinline__ unsigned short f2bf(float f) {
    unsigned u = __builtin_bit_cast(unsigned, f);
    u += 0x7fffu + ((u >> 16) & 1u);   // RNE
    return (unsigned short)(u >> 16);
}
__device__ __forceinline__ float bf2f(unsigned short u) {
    unsigned v = ((unsigned)u) << 16;
    return __builtin_bit_cast(float, v);
}

__device__ __forceinline__ float exp2_fast(float x) {
#if __has_builtin(__builtin_amdgcn_exp2f)
    return __builtin_amdgcn_exp2f(x);
#else
    float r;
    asm("v_exp_f32 %0, %1" : "=v"(r) : "v"(x));
    return r;
#endif
}

// ------------------------------------------------- W frag-order pack
__global__ __launch_bounds__(256) void transpose_w(
    const float* __restrict__ Wq,
    const float* __restrict__ Wk,
    const float* __restrict__ Wv,
    unsigned short* __restrict__ Ws)
{
    int o = blockIdx.x * 256 + threadIdx.x;   // 196608 total
    if (o < 196608) {
        int j    = o & 7;
        int l    = (o >> 3) & 63;
        int g    = (o >> 9) & 7;
        int rem  = o >> 12;        // sk*3 + mt
        int mt   = rem % 3;
        int sk   = rem / 3;
        int c    = g >> 2, nt = g & 3;
        int quad = l >> 4, n  = l & 15;
        int e    = sk * 64 + c * 32 + quad * 8 + j;
        int h    = nt * 16 + n;
        const float* W = (mt == 0) ? Wq : (mt == 1) ? Wk : Wv;
        Ws[o] = f2bf(W[e * 64 + h]);
    }
}

// ---------------------------------------------------------------- projection
// 512 blocks x 256 threads, 32 rows/block. 4 waves = ch (nt column) 0..3;
// all waves share the 32 rows. x staged via gload16 into 24 KB LDS (3 bufs,
// 2-deep counted-vmcnt); W JIT to registers (6 dwordx4/wave/step).
__global__ __launch_bounds__(256, 3) void proj_all(
    const float* __restrict__ x,             // [16384][1024] fp32
    const unsigned short* __restrict__ Ws,   // [16][3][8][64][8] bf16 frag-order
    unsigned short* __restrict__ Qo,         // [16384][64] bf16
    unsigned short* __restrict__ Ko,         // [16384][64] bf16
    unsigned short* __restrict__ Vto)        // [4][80][4096] bf16 (V^T)
{
    const int m0   = blockIdx.x * 32;
    const int tid  = threadIdx.x;
    const int lane = tid & 63;
    const int ch   = tid >> 6;     // 0..3 = nt column
    const int quad = lane >> 4;
    const int n    = lane & 15;

    __shared__ __align__(16) float xs[3][8][64][4];   // 24 KB

    const f32x4 zero4 = {0.f, 0.f, 0.f, 0.f};
    f32x4 acc[3][2];               // [mt][rg]
    #pragma unroll
    for (int mt = 0; mt < 3; ++mt)
        #pragma unroll
        for (int rg = 0; rg < 2; ++rg) acc[mt][rg] = zero4;

    // stage k-step t: exactly 2 gload16 per wave
    auto stage = [&](int t, int qb) {
        int k0 = t * 64;
        #pragma unroll
        for (int it = 0; it < 2; ++it) {
            int i     = ch + 4 * it;                 // 0..7 (row group of 4)
            int chunk = n ^ (quad << 2);
            gload16(x + (size_t)(m0 + 4 * i + quad) * 1024 + k0 + chunk * 4,
                    &xs[qb][i][0][0]);
        }
    };

    auto compute = [&](int t, int qb) {
        // W JIT: 6 panels straight to registers (coalesced 1 KB each)
        const unsigned short* wp = Ws + (((size_t)t * 24) << 9) + (size_t)lane * 8;
        short8 w0[3], w1[3];
        #pragma unroll
        for (int mt = 0; mt < 3; ++mt) {
            w0[mt] = *(const short8*)(wp + ((size_t)(mt * 8 + ch)     << 9));
            w1[mt] = *(const short8*)(wp + ((size_t)(mt * 8 + 4 + ch) << 9));
        }

        #pragma unroll
        for (int rg = 0; rg < 2; ++rg) {
            int sub = n & 3, s = sub << 2;
            const float* xp = &xs[qb][rg * 4 + (n >> 2)][0][0] + sub * 64;
            f32x4 u0 = *(const f32x4*)(xp + (((2 * quad)     ^ s) << 2));
            f32x4 u1 = *(const f32x4*)(xp + (((2 * quad + 1) ^ s) << 2));
            f32x4 u2 = *(const f32x4*)(xp + (((8 + 2 * quad) ^ s) << 2));
            f32x4 u3 = *(const f32x4*)(xp + (((9 + 2 * quad) ^ s) << 2));
            short8 a0, a1;
            #pragma unroll
            for (int j = 0; j < 4; ++j) {
                a0[j]     = (short)f2bf(u0[j]);
                a0[4 + j] = (short)f2bf(u1[j]);
                a1[j]     = (short)f2bf(u2[j]);
                a1[4 + j] = (short)f2bf(u3[j]);
            }
            #pragma unroll
            for (int mt = 0; mt < 3; ++mt) {
                acc[mt][rg] = MFMA16(a0, w0[mt], acc[mt][rg]);
                acc[mt][rg] = MFMA16(a1, w1[mt], acc[mt][rg]);
            }
        }
    };

    stage(0, 0);
    stage(1, 1);

    for (int t = 0; t < 15; ++t) {
        // stage(t) landed when <=2 of our loads remain (stage(t+1) in flight)
        asm volatile("s_waitcnt vmcnt(2)" ::: "memory");
        asm volatile("s_waitcnt lgkmcnt(0)" ::: "memory");
        __builtin_amdgcn_s_barrier();
        __builtin_amdgcn_sched_barrier(0);
        if (t < 14) stage(t + 2, (t + 2) % 3);
        compute(t, t % 3);
    }
    // peeled last iteration: full drain
    asm volatile("s_waitcnt vmcnt(0)" ::: "memory");
    asm volatile("s_waitcnt lgkmcnt(0)" ::: "memory");
    __builtin_amdgcn_s_barrier();
    __builtin_amdgcn_sched_barrier(0);
    compute(15, 0);

    const int h = ch * 16 + n;
    #pragma unroll
    for (int rg = 0; rg < 2; ++rg) {
        #pragma unroll
        for (int r = 0; r < 4; ++r) {
            int m = m0 + rg * 16 + quad * 4 + r;
            Qo[(size_t)m * 64 + h] = f2bf(acc[0][rg][r]);
            Ko[(size_t)m * 64 + h] = f2bf(acc[1][rg][r]);
            int b = m >> 12, s2 = m & 4095;
            Vto[((size_t)(b * 80 + h)) * 4096 + s2] = f2bf(acc[2][rg][r]);
        }
    }
}

// ---------------------------------------------------------------- attention
// 128-row Q-tile, 4 waves x 32 rows. 50 KB LDS -> 3 blocks/CU.
template <int SPLIT>
__device__ __forceinline__ void attn_body(
    const unsigned short* __restrict__ Q,
    const unsigned short* __restrict__ K,
    const unsigned short* __restrict__ Vt,   // [4][80][4096] (rows >=64 unused)
    float* __restrict__ dst,
    int b, int r0, int kt0, int kt1)
{
    const int tid  = threadIdx.x;
    const int lane = tid & 63;
    const int wv   = tid >> 6;     // 0..3
    const int quad = lane >> 4;
    const int n    = lane & 15;
    const int ktmask = r0 >> 6;

    __shared__ __align__(16) short kf[2][8][64][8];            // 16 KB
    __shared__ __align__(16) short vf[2][8][64][8];            // 16 KB
    __shared__ __align__(16) unsigned short pbuf[4][32][72];   // 18 KB

    // fold 0.125 (H^-0.5) * log2(e) so the score feeds v_exp_f32 (2^x) directly
    short8 qa[2][2];
    #pragma unroll
    for (int rg = 0; rg < 2; ++rg) {
        const unsigned short* qp =
            Q + (size_t)(b * 4096 + r0 + wv * 32 + rg * 16 + n) * 64 + quad * 8;
        #pragma unroll
        for (int j = 0; j < 8; ++j) {
            qa[rg][0][j] = (short)f2bf(bf2f(qp[j])      * 0.18033688f);
            qa[rg][1][j] = (short)f2bf(bf2f(qp[32 + j]) * 0.18033688f);
        }
    }

    const f32x4 zero4 = {0.f, 0.f, 0.f, 0.f};
    f32x4 oacc[2][4];
    float lacc[2][4];
    #pragma unroll
    for (int rg = 0; rg < 2; ++rg)
        #pragma unroll
        for (int nt = 0; nt < 4; ++nt) { oacc[rg][nt] = zero4; lacc[rg][nt] = 0.f; }

    const unsigned short* kbase = K  + ((size_t)b * 4096 + n) * 64 + quad * 8;
    const unsigned short* vbase = Vt + ((size_t)b * 80 + n) * 4096 + quad * 8;

    auto stage = [&](int kt, int p) {
        #pragma unroll
        for (int it = 0; it < 4; ++it) {
            int f = wv + 4 * it;               // 0..15, 4 loads per wave
            if (f < 8) {
                int c = f >> 2, nt = f & 3;
                gload16(kbase + (size_t)(kt * 64 + nt * 16) * 64 + c * 32, &kf[p][f][0][0]);
            } else {
                int pnl = f - 8;               // 0..7
                int nt = pnl >> 1, c = pnl & 1;
                gload16(vbase + (size_t)nt * 16 * 4096 + kt * 64 + c * 32, &vf[p][pnl][0][0]);
            }
        }
    };

    int p = 0;
    stage(kt0, 0);
    __syncthreads();

    for (int kt = kt0; kt <= kt1; ++kt) {
        if (kt < kt1) stage(kt + 1, p ^ 1);

        // QK^T: nt-outer so each kf panel is read once, frags live 8 VGPR
        f32x4 sacc[2][4];
        #pragma unroll
        for (int rg = 0; rg < 2; ++rg)
            #pragma unroll
            for (int nt = 0; nt < 4; ++nt) sacc[rg][nt] = zero4;

        #pragma unroll
        for (int nt = 0; nt < 4; ++nt) {
            short8 ka = *(const short8*)(&kf[p][nt][lane][0]);
            short8 kb = *(const short8*)(&kf[p][4 + nt][lane][0]);
            #pragma unroll
            for (int rg = 0; rg < 2; ++rg) {
                sacc[rg][nt] = MFMA16(qa[rg][0], ka, sacc[rg][nt]);
                sacc[rg][nt] = MFMA16(qa[rg][1], kb, sacc[rg][nt]);
            }
        }

        if (kt >= ktmask) {
            #pragma unroll
            for (int rg = 0; rg < 2; ++rg) {
                int qg = r0 + wv * 32 + rg * 16 + quad * 4;
                #pragma unroll
                for (int nt = 0; nt < 4; ++nt)
                    #pragma unroll
                    for (int r = 0; r < 4; ++r) {
                        int key = kt * 64 + nt * 16 + n;
                        if (key > qg + r) sacc[rg][nt][r] = -1e30f;
                    }
            }
        }

        // exp2 -> pbuf bf16 (manual RNE f2bf, R17-identical bits);
        // denominator summed from PRE-ROUNDING f32 values (drops 32 bf2f/iter;
        // <=2^-9 relative shift on the denominator, threshold 0.079).
        #pragma unroll
        for (int rg = 0; rg < 2; ++rg)
            #pragma unroll
            for (int r = 0; r < 4; ++r) {
                float rs = 0.f;
                #pragma unroll
                for (int nt = 0; nt < 4; ++nt) {
                    float pf = exp2_fast(sacc[rg][nt][r]);
                    pbuf[wv][rg * 16 + quad * 4 + r][nt * 16 + n] = f2bf(pf);
                    rs += pf;
                }
                lacc[rg][r] += rs;
            }

        // PV: nt-outer, vf panels read once
        short8 pa[2][2];
        #pragma unroll
        for (int rg = 0; rg < 2; ++rg) {
            pa[rg][0] = *(const short8*)(&pbuf[wv][rg * 16 + n][quad * 8]);
            pa[rg][1] = *(const short8*)(&pbuf[wv][rg * 16 + n][32 + quad * 8]);
        }
        #pragma unroll
        for (int nt = 0; nt < 4; ++nt) {
            short8 va = *(const short8*)(&vf[p][2 * nt][lane][0]);
            short8 vb = *(const short8*)(&vf[p][2 * nt + 1][lane][0]);
            #pragma unroll
            for (int rg = 0; rg < 2; ++rg) {
                oacc[rg][nt] = MFMA16(pa[rg][0], va, oacc[rg][nt]);
                oacc[rg][nt] = MFMA16(pa[rg][1], vb, oacc[rg][nt]);
            }
        }

        __syncthreads();
        p ^= 1;
    }

    // denominator: reduce over the 16 n-lanes of each quad group
    #pragma unroll
    for (int rg = 0; rg < 2; ++rg)
        #pragma unroll
        for (int r = 0; r < 4; ++r) {
            float v = lacc[rg][r];
            v += __shfl_xor(v, 1);
            v += __shfl_xor(v, 2);
            v += __shfl_xor(v, 4);
            v += __shfl_xor(v, 8);
            lacc[rg][r] = v;
        }

    if (SPLIT) {
        // record: O[128][64] fp32 (unnormalized) + l[128] at +8192
        #pragma unroll
        for (int rg = 0; rg < 2; ++rg)
            #pragma unroll
            for (int r = 0; r < 4; ++r) {
                int row = wv * 32 + rg * 16 + quad * 4 + r;
                #pragma unroll
                for (int nt = 0; nt < 4; ++nt)
                    dst[row * 64 + nt * 16 + n] = oacc[rg][nt][r];
                if (n == 0) dst[8192 + row] = lacc[rg][r];
            }
    } else {
        #pragma unroll
        for (int rg = 0; rg < 2; ++rg)
            #pragma unroll
            for (int r = 0; r < 4; ++r) {
                float inv = 1.f / lacc[rg][r];
                int q = r0 + wv * 32 + rg * 16 + quad * 4 + r;
                #pragma unroll
                for (int nt = 0; nt < 4; ++nt)
                    dst[(size_t)(b * 4096 + q) * 64 + nt * 16 + n] = oacc[rg][nt][r] * inv;
            }
    }
}

// Split-K: block -> (b, qtile128, chunk of 8 kt). 4 x 144 = 576 blocks.
__global__ __launch_bounds__(256, 3) void attn_part(
    const unsigned short* __restrict__ Q,
    const unsigned short* __restrict__ K,
    const unsigned short* __restrict__ Vt,
    float* __restrict__ Part)
{
    int id = blockIdx.x;
    int b  = id & 3;
    int t  = 143 - (id >> 2);              // heavy chunks first
    int g  = 0;
    while (2 * (g + 1) * (g + 2) <= t) ++g;
    int u  = t - 2 * g * (g + 1);
    int qt = 4 * g + u / (g + 1);
    int c  = u - (u / (g + 1)) * (g + 1);

    int r0  = qt * 128;
    int kt0 = c * 8;
    int kt1 = min(kt0 + 7, 2 * qt + 1);

    float* dst = Part + (size_t)(b * 144 + t) * 8320;
    attn_body<1>(Q, K, Vt, dst, b, r0, kt0, kt1);
}

// Monolithic fallback (ws too small).
__global__ __launch_bounds__(256, 3) void attn_mono(
    const unsigned short* __restrict__ Q,
    const unsigned short* __restrict__ K,
    const unsigned short* __restrict__ Vt,
    float* __restrict__ out)
{
    int id = blockIdx.x;
    int qt = 31 - (id >> 2);
    int b  = id & 3;
    attn_body<0>(Q, K, Vt, out, b, qt * 128, 0, 2 * qt + 1);
}

// ---------------------------------------------------------------- combine
// 1024 blocks = (4 b x 32 qt) x 8 slices of 16 rows. c-loop outermost with 4
// independent accumulators/thread.
__global__ __launch_bounds__(256) void combine(
    const float* __restrict__ Part, float* __restrict__ out)
{
    int id    = blockIdx.x;
    int slice = id & 7;                 // 16-row slice
    int bq    = id >> 3;
    int b     = bq & 3;
    int qt    = bq >> 2;
    int g     = qt >> 2;
    int nc    = g + 1;
    int t0    = 2 * g * (g + 1) + (qt & 3) * (g + 1);
    const float* P0 = Part + (size_t)(b * 144 + t0) * 8320;

    int tid = threadIdx.x;

    // denominators for this slice's 16 rows (parallel across c via 8 regs)
    __shared__ float invden[16];
    if (tid < 16) {
        float d[8] = {0, 0, 0, 0, 0, 0, 0, 0};
        #pragma unroll 8
        for (int c = 0; c < 8; ++c)
            if (c < nc) d[c] = P0[c * 8320 + 8192 + slice * 16 + tid];
        invden[tid] = 1.f / (((d[0] + d[1]) + (d[2] + d[3])) +
                             ((d[4] + d[5]) + (d[6] + d[7])));
    }

    // 1024 elements: 4 per thread, accumulate with c outermost
    float acc[4] = {0, 0, 0, 0};
    const float* Pe = P0 + slice * 1024 + tid;
    for (int c = 0; c < nc; ++c) {
        const float* Pc = Pe + (size_t)c * 8320;
        #pragma unroll
        for (int j = 0; j < 4; ++j)
            acc[j] += Pc[j * 256];
    }

    __syncthreads();
    #pragma unroll
    for (int j = 0; j < 4; ++j) {
        int e   = j * 256 + tid;            // within slice (1024 elems)
        int row = e >> 6;                   // local row 0..15
        out[((size_t)b * 4096 + qt * 128 + slice * 16) * 64 + (size_t)e]
            = acc[j] * invden[row];
    }
}

// ---------------------------------------------------------------- launcher
extern "C" void kernel_launch(void* const* d_in, const int* in_sizes, int n_in,
                              void* d_out, int out_size, void* d_ws, size_t ws_size,
                              hipStream_t stream) {
    const float* x  = (const float*)d_in[0];
    const float* Wq = (const float*)d_in[1];
    const float* Wk = (const float*)d_in[2];
    const float* Wv = (const float*)d_in[3];
    float* outp = (float*)d_out;
    unsigned short* ws = (unsigned short*)d_ws;

    // ws (bf16 elems): Q 1M | K 1M | Vt 4*80*4096 | Ws 192K, then fp32 partials
    unsigned short* Qw  = ws;
    unsigned short* Kw  = ws + 1048576;
    unsigned short* Vtw = ws + 2097152;            // 1310720 elems
    unsigned short* Wsp = ws + 3407872;            // 196608 elems -> end 3604480

    size_t part_off = ((size_t)3604480 * 2 + 255) & ~(size_t)255;
    size_t need     = part_off + (size_t)4 * 144 * 8320 * 4;
    float* Part = (float*)((char*)d_ws + part_off);

    transpose_w<<<dim3(768), dim3(256), 0, stream>>>(Wq, Wk, Wv, Wsp);
    proj_all<<<dim3(512), dim3(256), 0, stream>>>(x, Wsp, Qw, Kw, Vtw);

    if (ws_size >= need) {
        attn_part<<<dim3(576), dim3(256), 0, stream>>>(Qw, Kw, Vtw, Part);
        combine<<<dim3(1024), dim3(256), 0, stream>>>(Part, outp);
    } else {
        attn_mono<<<dim3(128), dim3(256), 0, stream>>>(Qw, Kw, Vtw, outp);
    }
}